// Round 1
// baseline (142.456 us; speedup 1.0000x reference)
//
#include <hip/hip_runtime.h>

#define N_FFT 1024
#define LOG2N 10
#define SPLIT0 513

// One block per row: 1024-point complex radix-2 DIT FFT in LDS (imag=0 input),
// write first 513 bins (real block, then imag block) to d_out.
__global__ __launch_bounds__(256) void fft1024_rows(const float* __restrict__ x,
                                                    float* __restrict__ out,
                                                    int nrows) {
    __shared__ float re[N_FFT];
    __shared__ float im[N_FFT];
    __shared__ float twr[N_FFT / 2];
    __shared__ float twi[N_FFT / 2];

    const int row = blockIdx.x;
    const int t = threadIdx.x;
    const float* __restrict__ xr = x + (size_t)row * N_FFT;

    // Twiddle table: W_1024^k = exp(-2*pi*i*k/1024), k in [0, 512)
    for (int k = t; k < N_FFT / 2; k += 256) {
        float ang = -6.2831853071795864769f * (float)k * (1.0f / (float)N_FFT);
        float s, c;
        __sincosf(ang, &s, &c);
        twr[k] = c;
        twi[k] = s;
    }

    // Coalesced global load; bit-reversed scatter into LDS.
    for (int i = t; i < N_FFT; i += 256) {
        float v = xr[i];
        int r = (int)(__brev((unsigned)i) >> (32 - LOG2N));
        re[r] = v;
        im[r] = 0.0f;
    }
    __syncthreads();

    // 10 radix-2 DIT stages; 512 butterflies/stage, 2 per thread.
    for (int s = 1; s <= LOG2N; ++s) {
        const int half = 1 << (s - 1);
        const int tshift = LOG2N - s;  // twiddle idx = j << tshift
        #pragma unroll 2
        for (int b = t; b < N_FFT / 2; b += 256) {
            const int j = b & (half - 1);
            const int grp = b >> (s - 1);
            const int p0 = (grp << s) + j;
            const int p1 = p0 + half;
            const float wr = twr[j << tshift];
            const float wi = twi[j << tshift];
            const float ar = re[p0], ai = im[p0];
            const float br_ = re[p1], bi_ = im[p1];
            const float tr = wr * br_ - wi * bi_;
            const float ti = wr * bi_ + wi * br_;
            re[p0] = ar + tr;
            im[p0] = ai + ti;
            re[p1] = ar - tr;
            im[p1] = ai - ti;
        }
        __syncthreads();
    }

    // Write first 513 bins: real plane then imag plane, both coalesced.
    float* __restrict__ outr = out + (size_t)row * SPLIT0;
    float* __restrict__ outi = out + (size_t)nrows * SPLIT0 + (size_t)row * SPLIT0;
    for (int k = t; k < SPLIT0; k += 256) {
        outr[k] = re[k];
        outi[k] = im[k];
    }
}

extern "C" void kernel_launch(void* const* d_in, const int* in_sizes, int n_in,
                              void* d_out, int out_size, void* d_ws, size_t ws_size,
                              hipStream_t stream) {
    const float* x = (const float*)d_in[0];
    float* out = (float*)d_out;
    const int nrows = in_sizes[0] / N_FFT;  // 16*512 = 8192
    fft1024_rows<<<nrows, 256, 0, stream>>>(x, out, nrows);
}

// Round 2
// 83.254 us; speedup vs baseline: 1.7111x; 1.7111x over previous
//
#include <hip/hip_runtime.h>

#define N_FFT 1024
#define SPLIT0 513
// Swizzle to break LDS bank conflicts: pad by 1 word every 32.
#define PAD(a) ((a) + ((a) >> 5))

// One block per PAIR of rows: z = row0 + i*row1, one 1024-pt complex FFT
// (radix-4 Stockham autosort, 5 passes), then untangle the two real spectra.
__global__ __launch_bounds__(256) void rfft1024_pairs(const float* __restrict__ x,
                                                      float* __restrict__ out,
                                                      int nrows) {
    __shared__ float bre[2][N_FFT + 32];
    __shared__ float bim[2][N_FFT + 32];

    const int t = threadIdx.x;
    const int pair = blockIdx.x;
    const float* __restrict__ r0 = x + (size_t)(2 * pair) * N_FFT;
    const float* __restrict__ r1 = r0 + N_FFT;

    // Load: z[i] = row0[i] + i*row1[i]; coalesced, conflict-free writes.
    #pragma unroll
    for (int c = 0; c < 4; ++c) {
        int i = t + 256 * c;
        bre[0][PAD(i)] = r0[i];
        bim[0][PAD(i)] = r1[i];
    }
    __syncthreads();

    const float CANG = -6.2831853071795864769f / 1024.0f;
    int src = 0;

    // 5 radix-4 Stockham DIF passes. Pass p: m = 4^p, l = 256/m.
    // Thread t: k = t % m, j = t / m. Reads src[t + 256r] (contiguous).
    // Twiddle on output r: exp(-2*pi*i * j*r/(4l)) ; j/(4l) = (t-k)/1024.
    // Writes dst[k + m*(4j + r)].
    #pragma unroll
    for (int p = 0; p < 5; ++p) {
        const int m = 1 << (2 * p);
        const int k = t & (m - 1);
        const int jm = t - k;  // j*m

        float ar = bre[src][PAD(t)],       ai = bim[src][PAD(t)];
        float br = bre[src][PAD(t + 256)], bi = bim[src][PAD(t + 256)];
        float cr = bre[src][PAD(t + 512)], ci = bim[src][PAD(t + 512)];
        float dr = bre[src][PAD(t + 768)], di = bim[src][PAD(t + 768)];

        // Radix-4 DIF butterfly: X0=a+b+c+d, X1=a-ib-c+id, X2=a-b+c-d, X3=a+ib-c-id
        float t0r = ar + cr, t0i = ai + ci;
        float t1r = ar - cr, t1i = ai - ci;
        float t2r = br + dr, t2i = bi + di;
        float t3r = br - dr, t3i = bi - di;

        float y0r = t0r + t2r, y0i = t0i + t2i;
        float y1r = t1r + t3i, y1i = t1i - t3r;  // t1 + (-i)*t3
        float y2r = t0r - t2r, y2i = t0i - t2i;
        float y3r = t1r - t3i, y3i = t1i + t3r;  // t1 - (-i)*t3

        // Twiddles: w1 = exp(-2*pi*i*(t-k)/1024); w2 = w1^2; w3 = w1*w2.
        float ang = CANG * (float)jm;
        float s1, c1;
        __sincosf(ang, &s1, &c1);
        float c2 = c1 * c1 - s1 * s1, s2 = 2.0f * c1 * s1;
        float c3 = c1 * c2 - s1 * s2, s3 = c1 * s2 + s1 * c2;

        float z1r = y1r * c1 - y1i * s1, z1i = y1r * s1 + y1i * c1;
        float z2r = y2r * c2 - y2i * s2, z2i = y2r * s2 + y2i * c2;
        float z3r = y3r * c3 - y3i * s3, z3i = y3r * s3 + y3i * c3;

        const int dst = src ^ 1;
        const int w0 = k + 4 * jm;
        bre[dst][PAD(w0)]          = y0r; bim[dst][PAD(w0)]          = y0i;
        bre[dst][PAD(w0 + m)]      = z1r; bim[dst][PAD(w0 + m)]      = z1i;
        bre[dst][PAD(w0 + 2 * m)]  = z2r; bim[dst][PAD(w0 + 2 * m)]  = z2i;
        bre[dst][PAD(w0 + 3 * m)]  = z3r; bim[dst][PAD(w0 + 3 * m)]  = z3i;
        __syncthreads();
        src ^= 1;
    }

    // Untangle: X0[k] = (Z[k]+conj(Z[N-k]))/2 ; X1[k] = -i/2*(Z[k]-conj(Z[N-k])).
    const size_t row0 = (size_t)(2 * pair);
    float* __restrict__ outr = out;
    float* __restrict__ outi = out + (size_t)nrows * SPLIT0;

    #pragma unroll
    for (int c = 0; c < 2; ++c) {
        int kk = t + 256 * c;
        float zr = bre[src][PAD(kk)], zi = bim[src][PAD(kk)];
        int km = (N_FFT - kk) & (N_FFT - 1);
        float mr = bre[src][PAD(km)], mi = bim[src][PAD(km)];
        float X0r = 0.5f * (zr + mr), X0i = 0.5f * (zi - mi);
        float X1r = 0.5f * (zi + mi), X1i = 0.5f * (mr - zr);
        outr[row0 * SPLIT0 + kk]       = X0r;
        outi[row0 * SPLIT0 + kk]       = X0i;
        outr[(row0 + 1) * SPLIT0 + kk] = X1r;
        outi[(row0 + 1) * SPLIT0 + kk] = X1i;
    }
    if (t == 0) {
        // k = 512 (Nyquist): Z[512] = X0[512] + i*X1[512], both real.
        float zr = bre[src][PAD(512)], zi = bim[src][PAD(512)];
        outr[row0 * SPLIT0 + 512]       = zr;
        outi[row0 * SPLIT0 + 512]       = 0.0f;
        outr[(row0 + 1) * SPLIT0 + 512] = zi;
        outi[(row0 + 1) * SPLIT0 + 512] = 0.0f;
    }
}

extern "C" void kernel_launch(void* const* d_in, const int* in_sizes, int n_in,
                              void* d_out, int out_size, void* d_ws, size_t ws_size,
                              hipStream_t stream) {
    const float* x = (const float*)d_in[0];
    float* out = (float*)d_out;
    const int nrows = in_sizes[0] / N_FFT;  // 8192
    rfft1024_pairs<<<nrows / 2, 256, 0, stream>>>(x, out, nrows);
}